// Round 1
// 1354.179 us; speedup vs baseline: 1.1074x; 1.1074x over previous
//
#include <hip/hip_runtime.h>

typedef __attribute__((ext_vector_type(8))) short bf16x8;
typedef __attribute__((ext_vector_type(4))) float f32x4;

__device__ __forceinline__ unsigned short f2bf(float f) {
  unsigned u = __builtin_bit_cast(unsigned, f);
  u += 0x7fffu + ((u >> 16) & 1u);  // round-to-nearest-even
  return (unsigned short)(u >> 16);
}
// hardware packed f32->bf16 (RNE), 1 instr per 2 values
__device__ __forceinline__ unsigned cvtpk(float lo, float hi) {
  unsigned r;
  asm("v_cvt_pk_bf16_f32 %0, %1, %2" : "=v"(r) : "v"(lo), "v"(hi));
  return r;
}
__device__ __forceinline__ bf16x8 pk8(f32x4 a, f32x4 b) {
  union { unsigned u[4]; bf16x8 v; } r;
  r.u[0] = cvtpk(a[0], a[1]);
  r.u[1] = cvtpk(a[2], a[3]);
  r.u[2] = cvtpk(b[0], b[1]);
  r.u[3] = cvtpk(b[2], b[3]);
  return r.v;
}
__device__ __forceinline__ bf16x8 zero8() {
  bf16x8 r;
#pragma unroll
  for (int i = 0; i < 8; ++i) r[i] = 0;
  return r;
}

// ======================= Phase A: GAT + masked maxpool =======================
// One wave per 16-node batch. Key ideas vs previous version:
//  - src/dst computed as ch @ (W@a_src/dst) in f32: no dependence on MFMA1,
//    32 FMAs + 4 shuffles instead of a 32-shuffle butterfly.
//  - node s+1 ch/A_c prefetched into regs at top of iteration s.
//  - only 18 KB LDS/block -> 3 blocks/CU at (256,3), vs 2 blocks before.
//  - pooled written to global (f32) for the separate GRU pass.
__global__ __launch_bounds__(256, 3) void gat_pool(
    const float* __restrict__ ch, const float* __restrict__ Ac,
    const int* __restrict__ ccnt, const float* __restrict__ W,
    const float* __restrict__ a_src, const float* __restrict__ a_dst,
    float* __restrict__ pooled, int N) {
  __shared__ __align__(16) unsigned short wT[64][72];  // W^T bf16 [h][k], 144B rows (2-way banks)
  __shared__ __align__(16) float wa[128];              // [0:64)=W@a_src, [64:128)=W@a_dst
  __shared__ __align__(16) float dstl[4][16];          // per-wave dst[c]
  __shared__ __align__(16) unsigned short wh_t[4][64][16];  // per-wave Wh^T bf16 [h][c]

  const int tid = threadIdx.x;
  for (int idx = tid; idx < 64 * 64; idx += 256) {
    wT[idx & 63][idx >> 6] = f2bf(W[idx]);  // W[k][h] -> wT[h][k]
  }
  if (tid < 128) {
    const int k = tid & 63;
    const float* av = (tid < 64) ? a_src : a_dst;
    float s = 0.f;
    for (int h = 0; h < 64; ++h) s += W[k * 64 + h] * av[h];
    wa[tid] = s;
  }
  __syncthreads();

  const int lane = tid & 63;
  const int w = tid >> 6;
  const int q = lane >> 4;
  const int m16 = lane & 15;
  const int qe = q & 1;

  // per-lane folded attention vectors: ws*[j] = (W@a_src)[32t+8q+j]
  const f32x4 ws0a = *(const f32x4*)&wa[8 * q];
  const f32x4 ws0b = *(const f32x4*)&wa[8 * q + 4];
  const f32x4 ws1a = *(const f32x4*)&wa[32 + 8 * q];
  const f32x4 ws1b = *(const f32x4*)&wa[36 + 8 * q];
  const f32x4 wd0a = *(const f32x4*)&wa[64 + 8 * q];
  const f32x4 wd0b = *(const f32x4*)&wa[68 + 8 * q];
  const f32x4 wd1a = *(const f32x4*)&wa[96 + 8 * q];
  const f32x4 wd1b = *(const f32x4*)&wa[100 + 8 * q];

  const int gwave = blockIdx.x * 4 + w;
  const int stride = gridDim.x * 4;
  const int nbatch = N >> 4;  // N divisible by 16
  for (int bidx = gwave; bidx < nbatch; bidx += stride) {
    const int nb = bidx << 4;
    const float* pch = ch + (size_t)nb * 1024 + m16 * 64 + 8 * q;
    const float* pac = Ac + (size_t)nb * 256 + m16 * 16 + 8 * qe;
    const int ccv = ccnt[nb + m16];  // 16 counts, lane m16
    f32x4 c0 = *(const f32x4*)pch;
    f32x4 c1 = *(const f32x4*)(pch + 4);
    f32x4 c2 = *(const f32x4*)(pch + 32);
    f32x4 c3 = *(const f32x4*)(pch + 36);
    f32x4 A0 = *(const f32x4*)pac;
    f32x4 A1 = *(const f32x4*)(pac + 4);

    for (int s = 0; s < 16; ++s) {
      const int n = nb + s;
      const int cc = __builtin_amdgcn_readlane(ccv, s);
      // ---- prefetch node s+1 (independent regs; overlaps whole body) ----
      f32x4 nc0, nc1, nc2, nc3, nA0, nA1;
      if (s < 15) {
        const float* p2 = pch + (size_t)(s + 1) * 1024;
        nc0 = *(const f32x4*)p2;
        nc1 = *(const f32x4*)(p2 + 4);
        nc2 = *(const f32x4*)(p2 + 32);
        nc3 = *(const f32x4*)(p2 + 36);
        const float* a2 = pac + (size_t)(s + 1) * 256;
        nA0 = *(const f32x4*)a2;
        nA1 = *(const f32x4*)(a2 + 4);
      }
      // ---- src/dst = ch . (W@a) : f32, independent of MFMA1 ----
      float ps = 0.f, pd = 0.f;
#pragma unroll
      for (int j = 0; j < 4; ++j) {
        ps += c0[j] * ws0a[j] + c1[j] * ws0b[j] + c2[j] * ws1a[j] + c3[j] * ws1b[j];
        pd += c0[j] * wd0a[j] + c1[j] * wd0b[j] + c2[j] * wd1a[j] + c3[j] * wd1b[j];
      }
      ps += __shfl_xor(ps, 16);
      ps += __shfl_xor(ps, 32);  // ps = src[m16] on all lanes
      pd += __shfl_xor(pd, 16);
      pd += __shfl_xor(pd, 32);
      if (q == 0) dstl[w][m16] = pd;
      // ---- A-frags for MFMA1 ----
      const bf16x8 afA0 = pk8(c0, c1);
      const bf16x8 afA1 = pk8(c2, c3);
      // ---- MFMA1: Wh = ch @ W ----
      f32x4 acc[4];
#pragma unroll
      for (int u = 0; u < 4; ++u) acc[u] = (f32x4){0.f, 0.f, 0.f, 0.f};
#pragma unroll
      for (int u = 0; u < 4; ++u) {
        acc[u] = __builtin_amdgcn_mfma_f32_16x16x32_bf16(
            afA0, *(const bf16x8*)&wT[16 * u + m16][8 * q], acc[u], 0, 0, 0);
        acc[u] = __builtin_amdgcn_mfma_f32_16x16x32_bf16(
            afA1, *(const bf16x8*)&wT[16 * u + m16][32 + 8 * q], acc[u], 0, 0, 0);
      }
      // ---- e + masked softmax (row i=m16, cols j=8*qe+jj) ----
      __threadfence_block();  // dstl visible
      const f32x4 d0 = *(const f32x4*)&dstl[w][8 * qe];
      const f32x4 d1 = *(const f32x4*)&dstl[w][8 * qe + 4];
      float p8[8];
      float rmax = -3.0e38f;
#pragma unroll
      for (int jj = 0; jj < 8; ++jj) {
        const float dstv = (jj < 4) ? d0[jj] : d1[jj - 4];
        const float av = (jj < 4) ? A0[jj] : A1[jj - 4];
        const float x = ps + dstv;
        const float e = fmaxf(x, 0.2f * x);  // leaky_relu(x, 0.2)
        const bool msk = (av > 0.5f) && (m16 < cc) && ((8 * qe + jj) < cc);
        p8[jj] = msk ? e : -1.0e9f;
        rmax = fmaxf(rmax, p8[jj]);
      }
      rmax = fmaxf(rmax, __shfl_xor(rmax, 16));
      float psum = 0.f;
#pragma unroll
      for (int jj = 0; jj < 8; ++jj) {
        p8[jj] = __expf(p8[jj] - rmax);
        psum += p8[jj];
      }
      psum += __shfl_xor(psum, 16);
      const float inv = 1.0f / psum;
      bf16x8 afrag2 = zero8();
      if (q < 2) {
        union { unsigned u[4]; bf16x8 v; } r;
#pragma unroll
        for (int jj = 0; jj < 4; ++jj)
          r.u[jj] = cvtpk(p8[2 * jj] * inv, p8[2 * jj + 1] * inv);
        afrag2 = r.v;
      }
      // ---- Wh -> bf16 LDS transpose for MFMA2 B-operand ----
#pragma unroll
      for (int u = 0; u < 4; ++u) {
        uint2 v;
        v.x = cvtpk(acc[u][0], acc[u][1]);
        v.y = cvtpk(acc[u][2], acc[u][3]);
        *(uint2*)&wh_t[w][16 * u + m16][4 * q] = v;
      }
      __threadfence_block();
      // ---- MFMA2 (h_msg = attn @ Wh) + elu + masked maxpool ----
      float pmv[4];
#pragma unroll
      for (int u = 0; u < 4; ++u) {
        bf16x8 bf2 = zero8();
        if (q < 2) bf2 = *(const bf16x8*)&wh_t[w][16 * u + m16][8 * q];
        const f32x4 z4 = (f32x4){0.f, 0.f, 0.f, 0.f};
        const f32x4 h4 =
            __builtin_amdgcn_mfma_f32_16x16x32_bf16(afrag2, bf2, z4, 0, 0, 0);
        float pm = -1.0e9f;
#pragma unroll
        for (int r = 0; r < 4; ++r) {
          const float v = h4[r];
          const float ev = v > 0.f ? v : __expf(v) - 1.0f;
          pm = fmaxf(pm, (4 * q + r) < cc ? ev : -1.0e9f);
        }
        pm = fmaxf(pm, __shfl_xor(pm, 16));
        pm = fmaxf(pm, __shfl_xor(pm, 32));
        pmv[u] = pm;
      }
      // lane stores col = 16q+m16 = lane: one contiguous 256B row
      const float sel = (q == 0) ? pmv[0] : (q == 1) ? pmv[1] : (q == 2) ? pmv[2] : pmv[3];
      pooled[(size_t)n * 64 + lane] = sel;
      if (s < 15) {
        c0 = nc0; c1 = nc1; c2 = nc2; c3 = nc3;
        A0 = nA0; A1 = nA1;
      }
    }  // s
  }
}

// ======================= Phase B: batched GRU (in-place) =====================
// Reads pooled (f32) from `hid`, rewrites `hid` with final hiddens.
// Safe in-place: each wave's stores only touch its own 16 rows, and every
// load of those rows (afP, pv) is data-consumed before the stores issue.
__global__ __launch_bounds__(256, 3) void gru_update(
    const float* __restrict__ nf, const float* __restrict__ Wx,
    const float* __restrict__ Whg, const float* __restrict__ bias,
    float* hid, int N) {
  __shared__ __align__(16) unsigned short whgT[192][72];  // [col][k], 144B rows
  __shared__ __align__(16) unsigned short wxT[192][40];   // [col][k<40], 80B rows
  __shared__ __align__(16) float b_lds[192];

  const int tid = threadIdx.x;
  for (int idx = tid; idx < 192 * 64; idx += 256) {
    const int col = idx % 192, k = idx / 192;
    whgT[col][k] = f2bf(Whg[k * 192 + col]);
    if (k < 40) wxT[col][k] = f2bf(Wx[k * 192 + col]);
  }
  if (tid < 192) b_lds[tid] = bias[tid];
  __syncthreads();

  const int lane = tid & 63;
  const int w = tid >> 6;
  const int q = lane >> 4;
  const int m16 = lane & 15;

  const int gwave = blockIdx.x * 4 + w;
  const int stride = gridDim.x * 4;
  const int nbatch = N >> 4;
  for (int bidx = gwave; bidx < nbatch; bidx += stride) {
    const int nb = bidx << 4;
    bf16x8 afP[2];  // A[m=node][k=h] from pooled (f32 in hid)
    {
      const float* p = hid + (size_t)(nb + m16) * 64 + 8 * q;
      const f32x4 v0 = *(const f32x4*)p;
      const f32x4 v1 = *(const f32x4*)(p + 4);
      const f32x4 v2 = *(const f32x4*)(p + 32);
      const f32x4 v3 = *(const f32x4*)(p + 36);
      afP[0] = pk8(v0, v1);
      afP[1] = pk8(v2, v3);
    }
    bf16x8 afX[2];  // A[m=node][k<40] from node_features
    {
      const float* p = nf + (size_t)(nb + m16) * 40 + 8 * q;
      const f32x4 v0 = *(const f32x4*)p;
      const f32x4 v1 = *(const f32x4*)(p + 4);
      afX[0] = pk8(v0, v1);
      afX[1] = zero8();
      if (q == 0) {
        const float* p1 = nf + (size_t)(nb + m16) * 40 + 32;
        const f32x4 w0 = *(const f32x4*)p1;
        const f32x4 w1 = *(const f32x4*)(p1 + 4);
        afX[1] = pk8(w0, w1);
      }
    }
    // pooled values needed in epilogue (f32, exact)
    float pv[4][4];
#pragma unroll
    for (int u = 0; u < 4; ++u)
#pragma unroll
      for (int r = 0; r < 4; ++r)
        pv[u][r] = hid[(size_t)(nb + 4 * q + r) * 64 + 16 * u + m16];

    f32x4 accS[8], accX4[4], accH4[4];
#pragma unroll
    for (int u = 0; u < 8; ++u) accS[u] = (f32x4){0.f, 0.f, 0.f, 0.f};
#pragma unroll
    for (int u = 0; u < 4; ++u) {
      accX4[u] = (f32x4){0.f, 0.f, 0.f, 0.f};
      accH4[u] = (f32x4){0.f, 0.f, 0.f, 0.f};
    }
    // cols 0..127 (z,r gates): gx+gh share an accumulator
#pragma unroll
    for (int u = 0; u < 8; ++u) {
      const int row = 16 * u + m16;
      accS[u] = __builtin_amdgcn_mfma_f32_16x16x32_bf16(
          afP[0], *(const bf16x8*)&whgT[row][8 * q], accS[u], 0, 0, 0);
      accS[u] = __builtin_amdgcn_mfma_f32_16x16x32_bf16(
          afX[0], *(const bf16x8*)&wxT[row][8 * q], accS[u], 0, 0, 0);
      accS[u] = __builtin_amdgcn_mfma_f32_16x16x32_bf16(
          afP[1], *(const bf16x8*)&whgT[row][32 + 8 * q], accS[u], 0, 0, 0);
      const bf16x8 bx1 = (q == 0) ? *(const bf16x8*)&wxT[row][32] : zero8();
      accS[u] = __builtin_amdgcn_mfma_f32_16x16x32_bf16(afX[1], bx1, accS[u], 0, 0, 0);
    }
    // cols 128..191 (n gate): separate gx/gh accumulators
#pragma unroll
    for (int u = 0; u < 4; ++u) {
      const int row = 128 + 16 * u + m16;
      accH4[u] = __builtin_amdgcn_mfma_f32_16x16x32_bf16(
          afP[0], *(const bf16x8*)&whgT[row][8 * q], accH4[u], 0, 0, 0);
      accX4[u] = __builtin_amdgcn_mfma_f32_16x16x32_bf16(
          afX[0], *(const bf16x8*)&wxT[row][8 * q], accX4[u], 0, 0, 0);
      accH4[u] = __builtin_amdgcn_mfma_f32_16x16x32_bf16(
          afP[1], *(const bf16x8*)&whgT[row][32 + 8 * q], accH4[u], 0, 0, 0);
      const bf16x8 bx1 = (q == 0) ? *(const bf16x8*)&wxT[row][32] : zero8();
      accX4[u] = __builtin_amdgcn_mfma_f32_16x16x32_bf16(afX[1], bx1, accX4[u], 0, 0, 0);
    }
    // epilogue: lane holds node 4q+r, col 16u+m16
#pragma unroll
    for (int u = 0; u < 4; ++u) {
      const int col = 16 * u + m16;
      const float bz = b_lds[col];
      const float br = b_lds[64 + col];
      const float bn = b_lds[128 + col];
#pragma unroll
      for (int r = 0; r < 4; ++r) {
        const float z = 1.0f / (1.0f + __expf(-(accS[u][r] + bz)));
        const float rg = 1.0f / (1.0f + __expf(-(accS[u + 4][r] + br)));
        const float nn = tanhf(accX4[u][r] + bn + rg * accH4[u][r]);
        hid[(size_t)(nb + 4 * q + r) * 64 + col] = (1.0f - z) * nn + z * pv[u][r];
      }
    }
  }
}

extern "C" void kernel_launch(void* const* d_in, const int* in_sizes, int n_in,
                              void* d_out, int out_size, void* d_ws, size_t ws_size,
                              hipStream_t stream) {
  const float* nf = (const float*)d_in[0];
  const float* ch = (const float*)d_in[1];
  const float* Ac = (const float*)d_in[2];
  const int* ccnt = (const int*)d_in[3];
  const float* W = (const float*)d_in[4];
  const float* a_src = (const float*)d_in[5];
  const float* a_dst = (const float*)d_in[6];
  const float* Wx = (const float*)d_in[7];
  const float* Whg = (const float*)d_in[8];
  const float* bias = (const float*)d_in[9];
  float* out = (float*)d_out;
  const int N = in_sizes[3];  // child_count is [N]
  const int nbatch = N >> 4;

  // Phase A: ~2 batches/wave at N=200k; 768 blocks resident (3/CU), rest backfill.
  int blocksA = 1563;
  if (blocksA > (nbatch + 3) / 4) blocksA = (nbatch + 3) / 4;
  if (blocksA < 1) blocksA = 1;
  hipLaunchKernelGGL(gat_pool, dim3(blocksA), dim3(256), 0, stream,
                     ch, Ac, ccnt, W, a_src, a_dst, out, N);

  // Phase B: in-place GRU over `out`.
  int blocksB = 782;
  if (blocksB > (nbatch + 3) / 4) blocksB = (nbatch + 3) / 4;
  if (blocksB < 1) blocksB = 1;
  hipLaunchKernelGGL(gru_update, dim3(blocksB), dim3(256), 0, stream,
                     nf, Wx, Whg, bias, out, N);
}